// Round 13
// baseline (1081.212 us; speedup 1.0000x reference)
//
#include <hip/hip_runtime.h>
#include <math.h>

// Transformer: DEPTH=4, DIM=768, HEADS=12, HD=64, CTX=2048, B=4.
// R17b: fix compile error (LDS pointer array -> addrspacecast static init
//       unsupported). Buffer bases now computed arithmetically from `cur`.
//       attn K/V LDS double-buffer -> ONE barrier per K-tile (was 2).
//       LDS 24->40KB, VGPR unchanged. Everything else identical to R16.

#define DEPTH 4
#define DIM   768
#define HEADS 12
#define HD    64
#define CTXN  2048
#define BATCH 4
#define TOKENS (BATCH * CTXN)   // 8192
#define QKVS  (3 * DIM)         // 2304

typedef unsigned short u16;
typedef short s16x8 __attribute__((ext_vector_type(8)));   // 8 bf16 (4 VGPRs)
typedef float f32x4 __attribute__((ext_vector_type(4)));   // MFMA acc
typedef u16  u16x4 __attribute__((ext_vector_type(4)));

// float -> bf16 bits, round-nearest-even (outputs that feed GEMMs)
__device__ __forceinline__ u16 f2bf(float f) {
  union { float f; unsigned u; } c;
  c.f = f;
  unsigned u = c.u;
  return (u16)((u + 0x7FFFu + ((u >> 16) & 1u)) >> 16);
}

// pack two f32 -> two bf16 (truncation) in ONE v_perm_b32:
// result = (hi16(hi)<<16) | hi16(lo). Builtin, not asm — scheduler-safe.
__device__ __forceinline__ unsigned pack_bf2(float lo, float hi) {
  union { float f; unsigned u; } a, b;
  a.f = lo; b.f = hi;
  return __builtin_amdgcn_perm(b.u, a.u, 0x07060302u);
}

// 64-elem-row bf16 tile helpers: 8-elem groups XOR-swizzled by (row&7).
__device__ __forceinline__ s16x8 ldfrag(const u16* t, int r, int g) {
  return *(const s16x8*)(t + r * 64 + 8 * (g ^ (r & 7)));
}
__device__ __forceinline__ void stfrag(u16* t, int r, int g, s16x8 v) {
  *(s16x8*)(t + r * 64 + 8 * (g ^ (r & 7))) = v;
}

// async 16B/lane global->LDS (lds dest = wave-uniform base + lane*16)
__device__ __forceinline__ void gld_lds16(const u16* g, u16* l) {
#if __has_builtin(__builtin_amdgcn_global_load_lds)
  __builtin_amdgcn_global_load_lds(
      (const __attribute__((address_space(1))) unsigned int*)g,
      (__attribute__((address_space(3))) unsigned int*)l, 16, 0, 0);
#else
  int lane = threadIdx.x & 63;
  *(s16x8*)(l + lane * 8) = *(const s16x8*)(g);
#endif
}

// ---------------------------------------------------------------- add pos emb
__global__ __launch_bounds__(256) void add_pos_kernel(
    const float* __restrict__ X, const float* __restrict__ P,
    float* __restrict__ Y, int n, int pn) {
  int i = blockIdx.x * 256 + threadIdx.x;
  if (i < n) Y[i] = X[i] + P[i % pn];
}

// ------------------------------------------- weight fp32 -> bf16 + transpose
__global__ __launch_bounds__(256) void wconv_kernel(
    const float* __restrict__ Wq, const float* __restrict__ Wk,
    const float* __restrict__ Wv, const float* __restrict__ Wo,
    const float* __restrict__ W1, const float* __restrict__ W2,
    u16* __restrict__ dst) {
  int mat = blockIdx.z;             // 0..23 = layer*6 + type
  int layer = mat / 6, type = mat % 6;
  const float* srcs[6] = {Wq, Wk, Wv, Wo, W1, W2};
  const float* src = srcs[type] + (size_t)layer * DIM * DIM;
  u16* d = dst + (size_t)mat * DIM * DIM;
  __shared__ float L[32][33];
  int k0 = blockIdx.y * 32, n0 = blockIdx.x * 32;
  int r = threadIdx.x >> 3, c4 = (threadIdx.x & 7) * 4;
  float4 v = *(const float4*)&src[(size_t)(k0 + r) * DIM + n0 + c4];
  L[c4 + 0][r] = v.x; L[c4 + 1][r] = v.y;
  L[c4 + 2][r] = v.z; L[c4 + 3][r] = v.w;
  __syncthreads();
  u16x4 w;
#pragma unroll
  for (int j = 0; j < 4; ++j) w[j] = f2bf(L[r][c4 + j]);
  *(u16x4*)&d[(size_t)(n0 + r) * DIM + k0 + c4] = w;
}

// ----------------------------------------------------- layernorm (bf16 out)
__global__ __launch_bounds__(256) void ln_kernel(
    const float* __restrict__ X, const float* __restrict__ g,
    const float* __restrict__ b, u16* __restrict__ Y) {
  int t = blockIdx.x;
  int tid = threadIdx.x;
  const float* xr = X + (size_t)t * DIM;
  float v0 = xr[tid], v1 = xr[tid + 256], v2 = xr[tid + 512];
  float s = v0 + v1 + v2;
  float q = v0 * v0 + v1 * v1 + v2 * v2;
#pragma unroll
  for (int o = 32; o > 0; o >>= 1) {
    s += __shfl_xor(s, o);
    q += __shfl_xor(q, o);
  }
  __shared__ float rs[4], rq[4];
  int w = tid >> 6;
  if ((tid & 63) == 0) { rs[w] = s; rq[w] = q; }
  __syncthreads();
  s = rs[0] + rs[1] + rs[2] + rs[3];
  q = rq[0] + rq[1] + rq[2] + rq[3];
  float mean = s * (1.0f / DIM);
  float var  = q * (1.0f / DIM) - mean * mean;
  float r = rsqrtf(var + 1e-5f);
  u16* yr = Y + (size_t)t * DIM;
  yr[tid]       = f2bf((v0 - mean) * r * g[tid]       + b[tid]);
  yr[tid + 256] = f2bf((v1 - mean) * r * g[tid + 256] + b[tid + 256]);
  yr[tid + 512] = f2bf((v2 - mean) * r * g[tid + 512] + b[tid + 512]);
}

// ------------------------------------------------------------ bf16 MFMA GEMM
// C[M=8192][Nc] = A[M][768] @ Bt[Nc][768]^T. Tile BM x 128, BK=64, async
// global_load_lds staging into the swizzled layout. Single-buffered
// 2-barrier K-loop (R9 form). OUT_VT: blocks with n0 >= 2*DIM write their
// (V-projection) output transposed into Vtw[b][h][d][t] instead of C.
template <int BM, int HAS_BIAS, int HAS_GELU, int HAS_RES, int OUT_BF16, int OUT_VT>
__global__ __launch_bounds__(256, 3) void gemm_bf16(
    const u16* __restrict__ A, const u16* __restrict__ Bt,
    const float* __restrict__ bias, void* __restrict__ Cv, int Nc,
    u16* __restrict__ Vtw) {
  constexpr int MI = BM / 32;           // acc row-frags per wave
  float* C = (float*)Cv;
  u16* Cb = (u16*)Cv;
  __shared__ __align__(16) u16 As[BM * 64];
  __shared__ __align__(16) u16 Bs[128 * 64];
  int tid = threadIdx.x;
  int wave = tid >> 6, lane = tid & 63, ln = lane & 15, quad = lane >> 4;
  int wr = wave >> 1, wc = wave & 1;

  // T1: bijective chunked XCD swizzle (grids are multiples of 8)
  int nwg = gridDim.x * gridDim.y;
  int lin = blockIdx.y * gridDim.x + blockIdx.x;
  int swz = (lin & 7) * (nwg >> 3) + (lin >> 3);
  int bx = swz % gridDim.x, by = swz / gridDim.x;
  int m0 = by * BM, n0 = bx * 128;

  // async staging source: lane fetches the group that lands at lds slot
  // lane*16 under the XOR swizzle: g = (lane&7) ^ ((lane>>3)&7)
  int sg = (lane & 7) ^ ((lane >> 3) & 7);
  int srowA = wave * (BM / 4) + (lane >> 3);
  int srowB = wave * 32 + (lane >> 3);
  const u16* ga = A + (size_t)(m0 + srowA) * DIM + sg * 8;
  const u16* gb = Bt + (size_t)(n0 + srowB) * DIM + sg * 8;
  u16* la = As + wave * (BM / 4) * 64;
  u16* lb = Bs + wave * 2048;

  f32x4 acc[MI][4];
  const f32x4 zero = {0.0f, 0.0f, 0.0f, 0.0f};
#pragma unroll
  for (int i = 0; i < MI; ++i)
#pragma unroll
    for (int j = 0; j < 4; ++j) acc[i][j] = zero;

  for (int kt = 0; kt < DIM / 64; ++kt) {
#pragma unroll
    for (int i = 0; i < MI; ++i)
      gld_lds16(ga + (size_t)i * 8 * DIM, la + i * 512);
#pragma unroll
    for (int i = 0; i < 4; ++i)
      gld_lds16(gb + (size_t)i * 8 * DIM, lb + i * 512);
    ga += 64; gb += 64;
    __syncthreads();

    s16x8 bfr0[4], bfr1[4];
#pragma unroll
    for (int ni = 0; ni < 4; ++ni) {
      bfr0[ni] = ldfrag(Bs, wc * 64 + ni * 16 + ln, quad);
      bfr1[ni] = ldfrag(Bs, wc * 64 + ni * 16 + ln, 4 + quad);
    }
#pragma unroll
    for (int mi = 0; mi < MI; ++mi) {
      s16x8 a0 = ldfrag(As, wr * (BM / 2) + mi * 16 + ln, quad);
      s16x8 a1 = ldfrag(As, wr * (BM / 2) + mi * 16 + ln, 4 + quad);
#pragma unroll
      for (int ni = 0; ni < 4; ++ni) {
        acc[mi][ni] = __builtin_amdgcn_mfma_f32_16x16x32_bf16(a0, bfr0[ni], acc[mi][ni], 0, 0, 0);
        acc[mi][ni] = __builtin_amdgcn_mfma_f32_16x16x32_bf16(a1, bfr1[ni], acc[mi][ni], 0, 0, 0);
      }
    }
    __syncthreads();
  }

  if (OUT_VT && n0 >= 2 * DIM) {
    // V-projection block: write transposed into Vtw[b][h][d][t].
    int bq = m0 / CTXN;
    int tb = m0 & (CTXN - 1);
#pragma unroll
    for (int ni = 0; ni < 4; ++ni) {
      int vc = (n0 - 2 * DIM) + wc * 64 + ni * 16 + ln;   // 0..767
      int hh = vc >> 6, dd = vc & 63;
      u16* vrow = Vtw + ((size_t)(bq * HEADS + hh) * HD + dd) * CTXN;
#pragma unroll
      for (int mi = 0; mi < MI; ++mi) {
        int t = tb + wr * (BM / 2) + mi * 16 + quad * 4;
        u16x4 w;
#pragma unroll
        for (int reg = 0; reg < 4; ++reg) w[reg] = f2bf(acc[mi][ni][reg]);
        *(u16x4*)&vrow[t] = w;
      }
    }
  } else {
#pragma unroll
    for (int ni = 0; ni < 4; ++ni) {
      int c = n0 + wc * 64 + ni * 16 + ln;
      float bv = HAS_BIAS ? bias[c] : 0.0f;
#pragma unroll
      for (int mi = 0; mi < MI; ++mi) {
#pragma unroll
        for (int reg = 0; reg < 4; ++reg) {
          int r = m0 + wr * (BM / 2) + mi * 16 + quad * 4 + reg;
          float v = acc[mi][ni][reg] + bv;
          if (HAS_GELU) v = 0.5f * v * (1.0f + erff(v * 0.70710678118654752f));
          size_t o = (size_t)r * Nc + c;
          if (OUT_BF16) { Cb[o] = f2bf(v); }
          else if (HAS_RES) { C[o] += v; }
          else { C[o] = v; }
        }
      }
    }
  }
}

// -------------------------------------------------- bf16 MFMA flash attention
// S^T formulation; defer-max; fmaf-folded scale; XCD-swizzled bid; setprio;
// Ps wave-private (no barrier); l-sum via MFMA; perm-pack P.
// R17: K/V LDS DOUBLE-BUFFER -> one barrier per K-tile. Loop k:
//   stfrag(buf^1, regs=t(k+1)); issue loads t(k+2); compute(buf); bar.
__global__ __launch_bounds__(256) void attn_kernel(
    const u16* __restrict__ QKV, const u16* __restrict__ Vt,
    u16* __restrict__ Ob) {
  const int tiles = CTXN / 64;
  const int nblk = BATCH * HEADS * tiles;  // 1536, %8==0
  int orig = blockIdx.x;
  int bid = (orig & 7) * (nblk >> 3) + (orig >> 3);  // T1 chunked swizzle
  int qt = bid % tiles;
  int h  = (bid / tiles) % HEADS;
  int b  = bid / (tiles * HEADS);
  int tid = threadIdx.x;
  int wave = tid >> 6, lane = tid & 63, ln = lane & 15, quad = lane >> 4;

  // layout: Ks0 [0,8K) Ks1 [8K,16K) Vs0 [16K,24K) Vs1 [24K,32K) Ps [32K,40K)
  __shared__ __align__(16) char smem[40960];
  u16* Ps = (u16*)(smem + 32768);  // P tile [q][kc] (wave-private rows)
  float (*Of)[65] = (float (*)[65])smem;  // epilogue overlay

  const u16* qrow =
      QKV + ((size_t)(b * CTXN + qt * 64 + wave * 16 + ln)) * QKVS + h * HD;
  s16x8 aq0 = *(const s16x8*)&qrow[quad * 8];
  s16x8 aq1 = *(const s16x8*)&qrow[32 + quad * 8];

  // all-ones bf16 B operand for the l-sum MFMA
  s16x8 ones;
#pragma unroll
  for (int j = 0; j < 8; ++j) ones[j] = (short)0x3F80;

  float m = -1e30f;
  f32x4 oacc[4], lacc;
  const f32x4 zero = {0.0f, 0.0f, 0.0f, 0.0f};
#pragma unroll
  for (int i = 0; i < 4; ++i) oacc[i] = zero;
  lacc = zero;

  const u16* kb0 = QKV + ((size_t)b * CTXN) * QKVS + DIM + h * HD;
  const u16* vt0 = Vt + ((size_t)(b * HEADS + h) * HD) * CTXN;
  const float lg = 0.125f * 1.4426950408889634f;  // scale * log2(e)
  const float THR = 44.3614195f;                  // 8 log2-units / lg

  // staging: thread owns rows sr0 (0..31), sr1 (32..63), group sg0.
  int sr0 = tid >> 3, sg0 = tid & 7;
  int sr1 = sr0 + 32;
  const u16* kp0 = kb0 + (size_t)sr0 * QKVS + sg0 * 8;
  const u16* kp1 = kb0 + (size_t)sr1 * QKVS + sg0 * 8;
  const u16* vp0 = vt0 + (size_t)sr0 * CTXN + sg0 * 8;
  const u16* vp1 = vt0 + (size_t)sr1 * CTXN + sg0 * 8;

  // prologue: tile 0 -> regs -> LDS buf0; tile 1 -> regs; one barrier.
  s16x8 rk0 = *(const s16x8*)kp0;
  s16x8 rk1 = *(const s16x8*)kp1;
  s16x8 rv0 = *(const s16x8*)vp0;
  s16x8 rv1 = *(const s16x8*)vp1;
  stfrag((u16*)smem, sr0, sg0, rk0);
  stfrag((u16*)smem, sr1, sg0, rk1);
  stfrag((u16*)(smem + 16384), sr0, sg0, rv0);
  stfrag((u16*)(smem + 16384), sr1, sg0, rv1);
  {
    int ktn = (tiles > 1) ? 1 : 0;
    rk0 = *(const s16x8*)(kp0 + (size_t)ktn * 64 * QKVS);
    rk1 = *(const s16x8*)(kp1 + (size_t)ktn * 64 * QKVS);
    rv0 = *(const s16x8*)(vp0 + (size_t)ktn * 64);
    rv1 = *(const s16x8*)(vp1 + (size_t)ktn * 64);
  }
  __syncthreads();

  for (int kt = 0; kt < tiles; ++kt) {
    int cur = kt & 1;
    const u16* Ks = (const u16*)(smem + (cur << 13));           // cur*8192
    const u16* Vs = (const u16*)(smem + 16384 + (cur << 13));

    // stage NEXT tile (t(k+1), held in regs) into buf^1 — no conflict with
    // this iter's reads of buf. Then issue loads for t(k+2).
    if (kt + 1 < tiles) {
      u16* Kn = (u16*)(smem + ((cur ^ 1) << 13));
      u16* Vn = (u16*)(smem + 16384 + ((cur ^ 1) << 13));
      stfrag(Kn, sr0, sg0, rk0);
      stfrag(Kn, sr1, sg0, rk1);
      stfrag(Vn, sr0, sg0, rv0);
      stfrag(Vn, sr1, sg0, rv1);
      int ktn = (kt + 2 < tiles) ? kt + 2 : tiles - 1;
      rk0 = *(const s16x8*)(kp0 + (size_t)ktn * 64 * QKVS);
      rk1 = *(const s16x8*)(kp1 + (size_t)ktn * 64 * QKVS);
      rv0 = *(const s16x8*)(vp0 + (size_t)ktn * 64);
      rv1 = *(const s16x8*)(vp1 + (size_t)ktn * 64);
    }

    f32x4 sacc[4];
    __builtin_amdgcn_s_setprio(1);
#pragma unroll
    for (int nb = 0; nb < 4; ++nb) {
      sacc[nb] = zero;
      s16x8 k0 = ldfrag(Ks, nb * 16 + ln, quad);
      s16x8 k1 = ldfrag(Ks, nb * 16 + ln, 4 + quad);
      sacc[nb] = __builtin_amdgcn_mfma_f32_16x16x32_bf16(k0, aq0, sacc[nb], 0, 0, 0);
      sacc[nb] = __builtin_amdgcn_mfma_f32_16x16x32_bf16(k1, aq1, sacc[nb], 0, 0, 0);
    }
    __builtin_amdgcn_s_setprio(0);

    // raw-domain tile max via v_max3 chains
    float mx = fmaxf(fmaxf(sacc[0][0], sacc[0][1]), sacc[0][2]);
    mx = fmaxf(fmaxf(mx, sacc[0][3]), sacc[1][0]);
    mx = fmaxf(fmaxf(mx, sacc[1][1]), sacc[1][2]);
    mx = fmaxf(fmaxf(mx, sacc[1][3]), sacc[2][0]);
    mx = fmaxf(fmaxf(mx, sacc[2][1]), sacc[2][2]);
    mx = fmaxf(fmaxf(mx, sacc[2][3]), sacc[3][0]);
    mx = fmaxf(fmaxf(mx, sacc[3][1]), sacc[3][2]);
    mx = fmaxf(mx, sacc[3][3]);
    mx = fmaxf(mx, __shfl_xor(mx, 16));
    mx = fmaxf(mx, __shfl_xor(mx, 32));

    // defer-max: only rescale when the running max grew past THR (wave-uniform)
    if (!__all(mx <= m + THR)) {
      float mnew = fmaxf(m, mx);
      float alpha = exp2f((m - mnew) * lg);
      float ar[4];
#pragma unroll
      for (int reg = 0; reg < 4; ++reg) ar[reg] = __shfl(alpha, quad * 4 + reg);
#pragma unroll
      for (int nb = 0; nb < 4; ++nb)
#pragma unroll
        for (int reg = 0; reg < 4; ++reg) oacc[nb][reg] *= ar[reg];
#pragma unroll
      for (int reg = 0; reg < 4; ++reg) lacc[reg] *= ar[reg];
      m = mnew;
    }

    float nm = -m * lg;
    uint2 pk[4];
#pragma unroll
    for (int nb = 0; nb < 4; ++nb) {
      float p0 = exp2f(fmaf(sacc[nb][0], lg, nm));
      float p1 = exp2f(fmaf(sacc[nb][1], lg, nm));
      float p2 = exp2f(fmaf(sacc[nb][2], lg, nm));
      float p3 = exp2f(fmaf(sacc[nb][3], lg, nm));
      pk[nb].x = pack_bf2(p0, p1);   // v_perm_b32: (hi16(p1)<<16)|hi16(p0)
      pk[nb].y = pack_bf2(p2, p3);
    }

    // P -> LDS: rows wave-private; same-wave DS ordering, no barrier.
    {
      int row = wave * 16 + ln;
      int rs = row & 7;
      int half = (quad & 1) * 4;
#pragma unroll
      for (int nb = 0; nb < 4; ++nb) {
        int g0 = nb * 2 + (quad >> 1);
        *(uint2*)&Ps[row * 64 + 8 * (g0 ^ rs) + half] = pk[nb];
      }
    }

    s16x8 ap0 = ldfrag(Ps, wave * 16 + ln, quad);
    s16x8 ap1 = ldfrag(Ps, wave * 16 + ln, 4 + quad);
    __builtin_amdgcn_s_setprio(1);
    // l-sum via matrix pipe: lacc += P @ ones (all columns equal)
    lacc = __builtin_amdgcn_mfma_f32_16x16x32_bf16(ap0, ones, lacc, 0, 0, 0);
    lacc = __builtin_amdgcn_mfma_f32_16x16x32_bf16(ap1, ones, lacc, 0, 0, 0);
#pragma unroll
    for (int nb = 0; nb < 4; ++nb) {
      s16x8 bv0 = ldfrag(Vs, nb * 16 + ln, quad);
      s16x8 bv1 = ldfrag(Vs, nb * 16 + ln, 4 + quad);
      oacc[nb] = __builtin_amdgcn_mfma_f32_16x16x32_bf16(ap0, bv0, oacc[nb], 0, 0, 0);
      oacc[nb] = __builtin_amdgcn_mfma_f32_16x16x32_bf16(ap1, bv1, oacc[nb], 0, 0, 0);
    }
    __builtin_amdgcn_s_setprio(0);
    // single barrier per tile: orders this iter's buf reads before the
    // next iter's stfrag overwrite of buf, and drains the t(k+2) loads
    // (covered by the full compute phase above).
    __syncthreads();
  }

  // lacc[reg] = l for q-row quad*4+reg — same indexing as oacc, no shuffle.
  float li[4];
#pragma unroll
  for (int reg = 0; reg < 4; ++reg) li[reg] = 1.0f / lacc[reg];

#pragma unroll
  for (int nb = 0; nb < 4; ++nb)
#pragma unroll
    for (int reg = 0; reg < 4; ++reg)
      Of[wave * 16 + quad * 4 + reg][nb * 16 + ln] = oacc[nb][reg] * li[reg];
  __syncthreads();
  {
    int r = tid >> 2, c0 = (tid & 3) * 16;
    u16* dst = Ob + ((size_t)(b * CTXN + qt * 64 + r)) * DIM + h * HD + c0;
#pragma unroll
    for (int k = 0; k < 4; ++k) {
      u16x4 w;
#pragma unroll
      for (int j = 0; j < 4; ++j) w[j] = f2bf(Of[r][c0 + 4 * k + j]);
      *(u16x4*)&dst[4 * k] = w;
    }
  }
}

// ------------------------------------------------------------------- launch
extern "C" void kernel_launch(void* const* d_in, const int* in_sizes, int n_in,
                              void* d_out, int out_size, void* d_ws, size_t ws_size,
                              hipStream_t stream) {
  const float* x_in  = (const float*)d_in[0];
  const float* pos   = (const float*)d_in[1];
  const float* ln1_g = (const float*)d_in[2];
  const float* ln1_b = (const float*)d_in[3];
  const float* Wq    = (const float*)d_in[4];
  const float* Wk    = (const float*)d_in[5];
  const float* Wv    = (const float*)d_in[6];
  const float* Wo    = (const float*)d_in[7];
  const float* ln2_g = (const float*)d_in[8];
  const float* ln2_b = (const float*)d_in[9];
  const float* W1    = (const float*)d_in[10];
  const float* b1    = (const float*)d_in[11];
  const float* W2    = (const float*)d_in[12];
  const float* b2    = (const float*)d_in[13];

  float* x = (float*)d_out;
  const size_t TD = (size_t)TOKENS * DIM;
  // ws layout (u16): hb(TD) | qkv(3TD) | vt(TD) | wt(24*WSZ); fb aliases qkv
  u16* hb  = (u16*)d_ws;
  u16* qkv = hb + TD;
  u16* vt  = qkv + 3 * TD;
  u16* wt  = vt + TD;
  u16* fb  = qkv;

  int n = (int)TD, pn = CTXN * DIM;
  add_pos_kernel<<<(n + 255) / 256, 256, 0, stream>>>(x_in, pos, x, n, pn);
  {
    dim3 wg(24, 24, 24);
    wconv_kernel<<<wg, 256, 0, stream>>>(Wq, Wk, Wv, Wo, W1, W2, wt);
  }

  const size_t WSZ = (size_t)DIM * DIM;
  dim3 gq(QKVS / 128, TOKENS / 64);   // (18, 128) BM=64 QKV, 2304 blocks
  dim3 gg(DIM / 128, TOKENS / 64);    // (6, 128) BM=64 tiles, 768 blocks
  int nblk_attn = BATCH * HEADS * (CTXN / 64);  // 1536
  for (int i = 0; i < DEPTH; ++i) {
    const u16* wqkv = wt + (size_t)(i * 6 + 0) * WSZ;  // [2304][768]
    const u16* wo   = wt + (size_t)(i * 6 + 3) * WSZ;
    const u16* w1   = wt + (size_t)(i * 6 + 4) * WSZ;
    const u16* w2   = wt + (size_t)(i * 6 + 5) * WSZ;

    // --- attention block ---
    ln_kernel<<<TOKENS, 256, 0, stream>>>(x, ln1_g + i * DIM, ln1_b + i * DIM, hb);
    gemm_bf16<64,0,0,0,1,1><<<gq, 256, 0, stream>>>(hb, wqkv, nullptr, qkv, QKVS, vt);
    attn_kernel<<<nblk_attn, 256, 0, stream>>>(qkv, vt, hb);
    gemm_bf16<64,0,0,1,0,0><<<gg, 256, 0, stream>>>(hb, wo, nullptr, x, DIM, nullptr);

    // --- feed-forward block ---
    ln_kernel<<<TOKENS, 256, 0, stream>>>(x, ln2_g + i * DIM, ln2_b + i * DIM, hb);
    gemm_bf16<64,1,1,0,1,0><<<gg, 256, 0, stream>>>(hb, w1, b1 + i * DIM, fb, DIM, nullptr);
    gemm_bf16<64,1,0,1,0,0><<<gg, 256, 0, stream>>>(fb, w2, b2 + i * DIM, x, DIM, nullptr);
  }
}

// Round 14
// 1035.279 us; speedup vs baseline: 1.0444x; 1.0444x over previous
//
#include <hip/hip_runtime.h>
#include <math.h>

// Transformer: DEPTH=4, DIM=768, HEADS=12, HD=64, CTX=2048, B=4.
// R18: REVERT to R16 exactly (best measured: 1038.8 µs). R17's K/V
//      double-buffer cut occupancy 34->28% and regressed attn 115.6->118.2
//      — the 2-barrier/24KB form wins on cross-block TLP.
//      State: vtrans fused into QKV epilogue (OUT_VT); attn = S^T form,
//      T14 reg-prefetch, defer-max, fmaf-folded scale, XCD swizzle,
//      setprio, wave-private Ps (no mid barrier), l-sum via ones-MFMA,
//      perm-pack P; GEMM = R9 single-buffer, BM=64, XCD swizzle.

#define DEPTH 4
#define DIM   768
#define HEADS 12
#define HD    64
#define CTXN  2048
#define BATCH 4
#define TOKENS (BATCH * CTXN)   // 8192
#define QKVS  (3 * DIM)         // 2304

typedef unsigned short u16;
typedef short s16x8 __attribute__((ext_vector_type(8)));   // 8 bf16 (4 VGPRs)
typedef float f32x4 __attribute__((ext_vector_type(4)));   // MFMA acc
typedef u16  u16x4 __attribute__((ext_vector_type(4)));

// float -> bf16 bits, round-nearest-even (outputs that feed GEMMs)
__device__ __forceinline__ u16 f2bf(float f) {
  union { float f; unsigned u; } c;
  c.f = f;
  unsigned u = c.u;
  return (u16)((u + 0x7FFFu + ((u >> 16) & 1u)) >> 16);
}

// pack two f32 -> two bf16 (truncation) in ONE v_perm_b32:
// result = (hi16(hi)<<16) | hi16(lo). Builtin, not asm — scheduler-safe.
__device__ __forceinline__ unsigned pack_bf2(float lo, float hi) {
  union { float f; unsigned u; } a, b;
  a.f = lo; b.f = hi;
  return __builtin_amdgcn_perm(b.u, a.u, 0x07060302u);
}

// 64-elem-row bf16 tile helpers: 8-elem groups XOR-swizzled by (row&7).
__device__ __forceinline__ s16x8 ldfrag(const u16* t, int r, int g) {
  return *(const s16x8*)(t + r * 64 + 8 * (g ^ (r & 7)));
}
__device__ __forceinline__ void stfrag(u16* t, int r, int g, s16x8 v) {
  *(s16x8*)(t + r * 64 + 8 * (g ^ (r & 7))) = v;
}

// async 16B/lane global->LDS (lds dest = wave-uniform base + lane*16)
__device__ __forceinline__ void gld_lds16(const u16* g, u16* l) {
#if __has_builtin(__builtin_amdgcn_global_load_lds)
  __builtin_amdgcn_global_load_lds(
      (const __attribute__((address_space(1))) unsigned int*)g,
      (__attribute__((address_space(3))) unsigned int*)l, 16, 0, 0);
#else
  int lane = threadIdx.x & 63;
  *(s16x8*)(l + lane * 8) = *(const s16x8*)(g);
#endif
}

// ---------------------------------------------------------------- add pos emb
__global__ __launch_bounds__(256) void add_pos_kernel(
    const float* __restrict__ X, const float* __restrict__ P,
    float* __restrict__ Y, int n, int pn) {
  int i = blockIdx.x * 256 + threadIdx.x;
  if (i < n) Y[i] = X[i] + P[i % pn];
}

// ------------------------------------------- weight fp32 -> bf16 + transpose
__global__ __launch_bounds__(256) void wconv_kernel(
    const float* __restrict__ Wq, const float* __restrict__ Wk,
    const float* __restrict__ Wv, const float* __restrict__ Wo,
    const float* __restrict__ W1, const float* __restrict__ W2,
    u16* __restrict__ dst) {
  int mat = blockIdx.z;             // 0..23 = layer*6 + type
  int layer = mat / 6, type = mat % 6;
  const float* srcs[6] = {Wq, Wk, Wv, Wo, W1, W2};
  const float* src = srcs[type] + (size_t)layer * DIM * DIM;
  u16* d = dst + (size_t)mat * DIM * DIM;
  __shared__ float L[32][33];
  int k0 = blockIdx.y * 32, n0 = blockIdx.x * 32;
  int r = threadIdx.x >> 3, c4 = (threadIdx.x & 7) * 4;
  float4 v = *(const float4*)&src[(size_t)(k0 + r) * DIM + n0 + c4];
  L[c4 + 0][r] = v.x; L[c4 + 1][r] = v.y;
  L[c4 + 2][r] = v.z; L[c4 + 3][r] = v.w;
  __syncthreads();
  u16x4 w;
#pragma unroll
  for (int j = 0; j < 4; ++j) w[j] = f2bf(L[r][c4 + j]);
  *(u16x4*)&d[(size_t)(n0 + r) * DIM + k0 + c4] = w;
}

// ----------------------------------------------------- layernorm (bf16 out)
__global__ __launch_bounds__(256) void ln_kernel(
    const float* __restrict__ X, const float* __restrict__ g,
    const float* __restrict__ b, u16* __restrict__ Y) {
  int t = blockIdx.x;
  int tid = threadIdx.x;
  const float* xr = X + (size_t)t * DIM;
  float v0 = xr[tid], v1 = xr[tid + 256], v2 = xr[tid + 512];
  float s = v0 + v1 + v2;
  float q = v0 * v0 + v1 * v1 + v2 * v2;
#pragma unroll
  for (int o = 32; o > 0; o >>= 1) {
    s += __shfl_xor(s, o);
    q += __shfl_xor(q, o);
  }
  __shared__ float rs[4], rq[4];
  int w = tid >> 6;
  if ((tid & 63) == 0) { rs[w] = s; rq[w] = q; }
  __syncthreads();
  s = rs[0] + rs[1] + rs[2] + rs[3];
  q = rq[0] + rq[1] + rq[2] + rq[3];
  float mean = s * (1.0f / DIM);
  float var  = q * (1.0f / DIM) - mean * mean;
  float r = rsqrtf(var + 1e-5f);
  u16* yr = Y + (size_t)t * DIM;
  yr[tid]       = f2bf((v0 - mean) * r * g[tid]       + b[tid]);
  yr[tid + 256] = f2bf((v1 - mean) * r * g[tid + 256] + b[tid + 256]);
  yr[tid + 512] = f2bf((v2 - mean) * r * g[tid + 512] + b[tid + 512]);
}

// ------------------------------------------------------------ bf16 MFMA GEMM
// C[M=8192][Nc] = A[M][768] @ Bt[Nc][768]^T. Tile BM x 128, BK=64, async
// global_load_lds staging into the swizzled layout. Single-buffered
// 2-barrier K-loop (R9 form). OUT_VT: blocks with n0 >= 2*DIM write their
// (V-projection) output transposed into Vtw[b][h][d][t] instead of C.
template <int BM, int HAS_BIAS, int HAS_GELU, int HAS_RES, int OUT_BF16, int OUT_VT>
__global__ __launch_bounds__(256, 3) void gemm_bf16(
    const u16* __restrict__ A, const u16* __restrict__ Bt,
    const float* __restrict__ bias, void* __restrict__ Cv, int Nc,
    u16* __restrict__ Vtw) {
  constexpr int MI = BM / 32;           // acc row-frags per wave
  float* C = (float*)Cv;
  u16* Cb = (u16*)Cv;
  __shared__ __align__(16) u16 As[BM * 64];
  __shared__ __align__(16) u16 Bs[128 * 64];
  int tid = threadIdx.x;
  int wave = tid >> 6, lane = tid & 63, ln = lane & 15, quad = lane >> 4;
  int wr = wave >> 1, wc = wave & 1;

  // T1: bijective chunked XCD swizzle (grids are multiples of 8)
  int nwg = gridDim.x * gridDim.y;
  int lin = blockIdx.y * gridDim.x + blockIdx.x;
  int swz = (lin & 7) * (nwg >> 3) + (lin >> 3);
  int bx = swz % gridDim.x, by = swz / gridDim.x;
  int m0 = by * BM, n0 = bx * 128;

  // async staging source: lane fetches the group that lands at lds slot
  // lane*16 under the XOR swizzle: g = (lane&7) ^ ((lane>>3)&7)
  int sg = (lane & 7) ^ ((lane >> 3) & 7);
  int srowA = wave * (BM / 4) + (lane >> 3);
  int srowB = wave * 32 + (lane >> 3);
  const u16* ga = A + (size_t)(m0 + srowA) * DIM + sg * 8;
  const u16* gb = Bt + (size_t)(n0 + srowB) * DIM + sg * 8;
  u16* la = As + wave * (BM / 4) * 64;
  u16* lb = Bs + wave * 2048;

  f32x4 acc[MI][4];
  const f32x4 zero = {0.0f, 0.0f, 0.0f, 0.0f};
#pragma unroll
  for (int i = 0; i < MI; ++i)
#pragma unroll
    for (int j = 0; j < 4; ++j) acc[i][j] = zero;

  for (int kt = 0; kt < DIM / 64; ++kt) {
#pragma unroll
    for (int i = 0; i < MI; ++i)
      gld_lds16(ga + (size_t)i * 8 * DIM, la + i * 512);
#pragma unroll
    for (int i = 0; i < 4; ++i)
      gld_lds16(gb + (size_t)i * 8 * DIM, lb + i * 512);
    ga += 64; gb += 64;
    __syncthreads();

    s16x8 bfr0[4], bfr1[4];
#pragma unroll
    for (int ni = 0; ni < 4; ++ni) {
      bfr0[ni] = ldfrag(Bs, wc * 64 + ni * 16 + ln, quad);
      bfr1[ni] = ldfrag(Bs, wc * 64 + ni * 16 + ln, 4 + quad);
    }
#pragma unroll
    for (int mi = 0; mi < MI; ++mi) {
      s16x8 a0 = ldfrag(As, wr * (BM / 2) + mi * 16 + ln, quad);
      s16x8 a1 = ldfrag(As, wr * (BM / 2) + mi * 16 + ln, 4 + quad);
#pragma unroll
      for (int ni = 0; ni < 4; ++ni) {
        acc[mi][ni] = __builtin_amdgcn_mfma_f32_16x16x32_bf16(a0, bfr0[ni], acc[mi][ni], 0, 0, 0);
        acc[mi][ni] = __builtin_amdgcn_mfma_f32_16x16x32_bf16(a1, bfr1[ni], acc[mi][ni], 0, 0, 0);
      }
    }
    __syncthreads();
  }

  if (OUT_VT && n0 >= 2 * DIM) {
    // V-projection block: write transposed into Vtw[b][h][d][t].
    int bq = m0 / CTXN;
    int tb = m0 & (CTXN - 1);
#pragma unroll
    for (int ni = 0; ni < 4; ++ni) {
      int vc = (n0 - 2 * DIM) + wc * 64 + ni * 16 + ln;   // 0..767
      int hh = vc >> 6, dd = vc & 63;
      u16* vrow = Vtw + ((size_t)(bq * HEADS + hh) * HD + dd) * CTXN;
#pragma unroll
      for (int mi = 0; mi < MI; ++mi) {
        int t = tb + wr * (BM / 2) + mi * 16 + quad * 4;
        u16x4 w;
#pragma unroll
        for (int reg = 0; reg < 4; ++reg) w[reg] = f2bf(acc[mi][ni][reg]);
        *(u16x4*)&vrow[t] = w;
      }
    }
  } else {
#pragma unroll
    for (int ni = 0; ni < 4; ++ni) {
      int c = n0 + wc * 64 + ni * 16 + ln;
      float bv = HAS_BIAS ? bias[c] : 0.0f;
#pragma unroll
      for (int mi = 0; mi < MI; ++mi) {
#pragma unroll
        for (int reg = 0; reg < 4; ++reg) {
          int r = m0 + wr * (BM / 2) + mi * 16 + quad * 4 + reg;
          float v = acc[mi][ni][reg] + bv;
          if (HAS_GELU) v = 0.5f * v * (1.0f + erff(v * 0.70710678118654752f));
          size_t o = (size_t)r * Nc + c;
          if (OUT_BF16) { Cb[o] = f2bf(v); }
          else if (HAS_RES) { C[o] += v; }
          else { C[o] = v; }
        }
      }
    }
  }
}

// -------------------------------------------------- bf16 MFMA flash attention
// S^T formulation; T14 reg-prefetch staging; defer-max; fmaf-folded scale;
// XCD-swizzled bid; setprio; Ps wave-private (no barrier); l-sum via MFMA;
// P packed to bf16 pairs with v_perm_b32. R16 form (best measured).
__global__ __launch_bounds__(256) void attn_kernel(
    const u16* __restrict__ QKV, const u16* __restrict__ Vt,
    u16* __restrict__ Ob) {
  const int tiles = CTXN / 64;
  const int nblk = BATCH * HEADS * tiles;  // 1536, %8==0
  int orig = blockIdx.x;
  int bid = (orig & 7) * (nblk >> 3) + (orig >> 3);  // T1 chunked swizzle
  int qt = bid % tiles;
  int h  = (bid / tiles) % HEADS;
  int b  = bid / (tiles * HEADS);
  int tid = threadIdx.x;
  int wave = tid >> 6, lane = tid & 63, ln = lane & 15, quad = lane >> 4;

  __shared__ __align__(16) char smem[24576];
  u16* Ks = (u16*)smem;            // K tile  [kc][d]
  u16* Vs = (u16*)(smem + 8192);   // V^T tile [d][kc]
  u16* Ps = (u16*)(smem + 16384);  // P tile  [q][kc] (wave-private rows)
  float (*Of)[65] = (float (*)[65])smem;

  const u16* qrow =
      QKV + ((size_t)(b * CTXN + qt * 64 + wave * 16 + ln)) * QKVS + h * HD;
  s16x8 aq0 = *(const s16x8*)&qrow[quad * 8];
  s16x8 aq1 = *(const s16x8*)&qrow[32 + quad * 8];

  // all-ones bf16 B operand for the l-sum MFMA
  s16x8 ones;
#pragma unroll
  for (int j = 0; j < 8; ++j) ones[j] = (short)0x3F80;

  float m = -1e30f;
  f32x4 oacc[4], lacc;
  const f32x4 zero = {0.0f, 0.0f, 0.0f, 0.0f};
#pragma unroll
  for (int i = 0; i < 4; ++i) oacc[i] = zero;
  lacc = zero;

  const u16* kb0 = QKV + ((size_t)b * CTXN) * QKVS + DIM + h * HD;
  const u16* vt0 = Vt + ((size_t)(b * HEADS + h) * HD) * CTXN;
  const float lg = 0.125f * 1.4426950408889634f;  // scale * log2(e)
  const float THR = 44.3614195f;                  // 8 log2-units / lg

  // T14 staging: each thread owns rows sr0 (0..31) and sr1 (32..63), group sg0.
  int sr0 = tid >> 3, sg0 = tid & 7;
  int sr1 = sr0 + 32;
  const u16* kp0 = kb0 + (size_t)sr0 * QKVS + sg0 * 8;
  const u16* kp1 = kb0 + (size_t)sr1 * QKVS + sg0 * 8;
  const u16* vp0 = vt0 + (size_t)sr0 * CTXN + sg0 * 8;
  const u16* vp1 = vt0 + (size_t)sr1 * CTXN + sg0 * 8;

  // prologue: tile 0 into regs
  s16x8 rk0 = *(const s16x8*)kp0;
  s16x8 rk1 = *(const s16x8*)kp1;
  s16x8 rv0 = *(const s16x8*)vp0;
  s16x8 rv1 = *(const s16x8*)vp1;

  for (int kt = 0; kt < tiles; ++kt) {
    // write current tile from regs to LDS
    stfrag(Ks, sr0, sg0, rk0);
    stfrag(Ks, sr1, sg0, rk1);
    stfrag(Vs, sr0, sg0, rv0);
    stfrag(Vs, sr1, sg0, rv1);
    __syncthreads();

    // issue next-tile loads immediately; they fly under QK^T+softmax+PV.
    {
      int ktn = (kt + 1 < tiles) ? kt + 1 : kt;  // clamp: last iter re-reads
      rk0 = *(const s16x8*)(kp0 + (size_t)ktn * 64 * QKVS);
      rk1 = *(const s16x8*)(kp1 + (size_t)ktn * 64 * QKVS);
      rv0 = *(const s16x8*)(vp0 + (size_t)ktn * 64);
      rv1 = *(const s16x8*)(vp1 + (size_t)ktn * 64);
    }

    f32x4 sacc[4];
    __builtin_amdgcn_s_setprio(1);
#pragma unroll
    for (int nb = 0; nb < 4; ++nb) {
      sacc[nb] = zero;
      s16x8 k0 = ldfrag(Ks, nb * 16 + ln, quad);
      s16x8 k1 = ldfrag(Ks, nb * 16 + ln, 4 + quad);
      sacc[nb] = __builtin_amdgcn_mfma_f32_16x16x32_bf16(k0, aq0, sacc[nb], 0, 0, 0);
      sacc[nb] = __builtin_amdgcn_mfma_f32_16x16x32_bf16(k1, aq1, sacc[nb], 0, 0, 0);
    }
    __builtin_amdgcn_s_setprio(0);

    // raw-domain tile max via v_max3 chains (8 ops vs 15)
    float mx = fmaxf(fmaxf(sacc[0][0], sacc[0][1]), sacc[0][2]);
    mx = fmaxf(fmaxf(mx, sacc[0][3]), sacc[1][0]);
    mx = fmaxf(fmaxf(mx, sacc[1][1]), sacc[1][2]);
    mx = fmaxf(fmaxf(mx, sacc[1][3]), sacc[2][0]);
    mx = fmaxf(fmaxf(mx, sacc[2][1]), sacc[2][2]);
    mx = fmaxf(fmaxf(mx, sacc[2][3]), sacc[3][0]);
    mx = fmaxf(fmaxf(mx, sacc[3][1]), sacc[3][2]);
    mx = fmaxf(mx, sacc[3][3]);
    mx = fmaxf(mx, __shfl_xor(mx, 16));
    mx = fmaxf(mx, __shfl_xor(mx, 32));

    // defer-max: only rescale when the running max grew past THR (wave-uniform)
    if (!__all(mx <= m + THR)) {
      float mnew = fmaxf(m, mx);
      float alpha = exp2f((m - mnew) * lg);
      float ar[4];
#pragma unroll
      for (int reg = 0; reg < 4; ++reg) ar[reg] = __shfl(alpha, quad * 4 + reg);
#pragma unroll
      for (int nb = 0; nb < 4; ++nb)
#pragma unroll
        for (int reg = 0; reg < 4; ++reg) oacc[nb][reg] *= ar[reg];
#pragma unroll
      for (int reg = 0; reg < 4; ++reg) lacc[reg] *= ar[reg];
      m = mnew;
    }

    float nm = -m * lg;
    uint2 pk[4];
#pragma unroll
    for (int nb = 0; nb < 4; ++nb) {
      float p0 = exp2f(fmaf(sacc[nb][0], lg, nm));
      float p1 = exp2f(fmaf(sacc[nb][1], lg, nm));
      float p2 = exp2f(fmaf(sacc[nb][2], lg, nm));
      float p3 = exp2f(fmaf(sacc[nb][3], lg, nm));
      pk[nb].x = pack_bf2(p0, p1);   // v_perm_b32: (hi16(p1)<<16)|hi16(p0)
      pk[nb].y = pack_bf2(p2, p3);
    }

    // P -> LDS: rows wave-private (row = wave*16+ln); PV below reads the
    // same rows. Same-wave DS ordering (in-order LDS pipe) suffices — no
    // barrier needed between write and read.
    {
      int row = wave * 16 + ln;
      int rs = row & 7;
      int half = (quad & 1) * 4;
#pragma unroll
      for (int nb = 0; nb < 4; ++nb) {
        int g0 = nb * 2 + (quad >> 1);
        *(uint2*)&Ps[row * 64 + 8 * (g0 ^ rs) + half] = pk[nb];
      }
    }

    s16x8 ap0 = ldfrag(Ps, wave * 16 + ln, quad);
    s16x8 ap1 = ldfrag(Ps, wave * 16 + ln, 4 + quad);
    __builtin_amdgcn_s_setprio(1);
    // l-sum via matrix pipe: lacc += P @ ones (all columns equal)
    lacc = __builtin_amdgcn_mfma_f32_16x16x32_bf16(ap0, ones, lacc, 0, 0, 0);
    lacc = __builtin_amdgcn_mfma_f32_16x16x32_bf16(ap1, ones, lacc, 0, 0, 0);
#pragma unroll
    for (int nb = 0; nb < 4; ++nb) {
      s16x8 bv0 = ldfrag(Vs, nb * 16 + ln, quad);
      s16x8 bv1 = ldfrag(Vs, nb * 16 + ln, 4 + quad);
      oacc[nb] = __builtin_amdgcn_mfma_f32_16x16x32_bf16(ap0, bv0, oacc[nb], 0, 0, 0);
      oacc[nb] = __builtin_amdgcn_mfma_f32_16x16x32_bf16(ap1, bv1, oacc[nb], 0, 0, 0);
    }
    __builtin_amdgcn_s_setprio(0);
    __syncthreads();
  }

  // lacc[reg] = l for q-row quad*4+reg — same indexing as oacc, no shuffle.
  float li[4];
#pragma unroll
  for (int reg = 0; reg < 4; ++reg) li[reg] = 1.0f / lacc[reg];

#pragma unroll
  for (int nb = 0; nb < 4; ++nb)
#pragma unroll
    for (int reg = 0; reg < 4; ++reg)
      Of[wave * 16 + quad * 4 + reg][nb * 16 + ln] = oacc[nb][reg] * li[reg];
  __syncthreads();
  {
    int r = tid >> 2, c0 = (tid & 3) * 16;
    u16* dst = Ob + ((size_t)(b * CTXN + qt * 64 + r)) * DIM + h * HD + c0;
#pragma unroll
    for (int k = 0; k < 4; ++k) {
      u16x4 w;
#pragma unroll
      for (int j = 0; j < 4; ++j) w[j] = f2bf(Of[r][c0 + 4 * k + j]);
      *(u16x4*)&dst[4 * k] = w;
    }
  }
}

// ------------------------------------------------------------------- launch
extern "C" void kernel_launch(void* const* d_in, const int* in_sizes, int n_in,
                              void* d_out, int out_size, void* d_ws, size_t ws_size,
                              hipStream_t stream) {
  const float* x_in  = (const float*)d_in[0];
  const float* pos   = (const float*)d_in[1];
  const float* ln1_g = (const float*)d_in[2];
  const float* ln1_b = (const float*)d_in[3];
  const float* Wq    = (const float*)d_in[4];
  const float* Wk    = (const float*)d_in[5];
  const float* Wv    = (const float*)d_in[6];
  const float* Wo    = (const float*)d_in[7];
  const float* ln2_g = (const float*)d_in[8];
  const float* ln2_b = (const float*)d_in[9];
  const float* W1    = (const float*)d_in[10];
  const float* b1    = (const float*)d_in[11];
  const float* W2    = (const float*)d_in[12];
  const float* b2    = (const float*)d_in[13];

  float* x = (float*)d_out;
  const size_t TD = (size_t)TOKENS * DIM;
  // ws layout (u16): hb(TD) | qkv(3TD) | vt(TD) | wt(24*WSZ); fb aliases qkv
  u16* hb  = (u16*)d_ws;
  u16* qkv = hb + TD;
  u16* vt  = qkv + 3 * TD;
  u16* wt  = vt + TD;
  u16* fb  = qkv;

  int n = (int)TD, pn = CTXN * DIM;
  add_pos_kernel<<<(n + 255) / 256, 256, 0, stream>>>(x_in, pos, x, n, pn);
  {
    dim3 wg(24, 24, 24);
    wconv_kernel<<<wg, 256, 0, stream>>>(Wq, Wk, Wv, Wo, W1, W2, wt);
  }

  const size_t WSZ = (size_t)DIM * DIM;
  dim3 gq(QKVS / 128, TOKENS / 64);   // (18, 128) BM=64 QKV, 2304 blocks
  dim3 gg(DIM / 128, TOKENS / 64);    // (6, 128) BM=64 tiles, 768 blocks
  int nblk_attn = BATCH * HEADS * (CTXN / 64);  // 1536
  for (int i = 0; i < DEPTH; ++i) {
    const u16* wqkv = wt + (size_t)(i * 6 + 0) * WSZ;  // [2304][768]
    const u16* wo   = wt + (size_t)(i * 6 + 3) * WSZ;
    const u16* w1   = wt + (size_t)(i * 6 + 4) * WSZ;
    const u16* w2   = wt + (size_t)(i * 6 + 5) * WSZ;

    // --- attention block ---
    ln_kernel<<<TOKENS, 256, 0, stream>>>(x, ln1_g + i * DIM, ln1_b + i * DIM, hb);
    gemm_bf16<64,0,0,0,1,1><<<gq, 256, 0, stream>>>(hb, wqkv, nullptr, qkv, QKVS, vt);
    attn_kernel<<<nblk_attn, 256, 0, stream>>>(qkv, vt, hb);
    gemm_bf16<64,0,0,1,0,0><<<gg, 256, 0, stream>>>(hb, wo, nullptr, x, DIM, nullptr);

    // --- feed-forward block ---
    ln_kernel<<<TOKENS, 256, 0, stream>>>(x, ln2_g + i * DIM, ln2_b + i * DIM, hb);
    gemm_bf16<64,1,1,0,1,0><<<gg, 256, 0, stream>>>(hb, w1, b1 + i * DIM, fb, DIM, nullptr);
    gemm_bf16<64,1,0,1,0,0><<<gg, 256, 0, stream>>>(fb, w2, b2 + i * DIM, x, DIM, nullptr);
  }
}